// Round 5
// baseline (460.872 us; speedup 1.0000x reference)
//
#include <hip/hip_runtime.h>
#include <hip/hip_bf16.h>
#include <math.h>

// Problem constants
#define B_ 2
#define T_ 2048
#define C_ 2048
#define H_ 16
#define HD_ 128
#define LORA_ 512
#define RD_ 64
#define ND_ 64
#define BT_ (B_*T_)            // 4096
#define NKVA_ 576              // LORA + RD
#define NKVAP_ 640             // padded to 128
#define LOG2_THETA 16.609640474436812f

typedef __bf16 bf16x8 __attribute__((ext_vector_type(8)));
typedef float  f32x4  __attribute__((ext_vector_type(4)));

#define MFMA16(a,b,c) __builtin_amdgcn_mfma_f32_16x16x32_bf16((a),(b),(c),0,0,0)

// global -> LDS direct 16B copy (lds dest must be wave-uniform base + lane*16)
__device__ static inline void load_lds16(const __bf16* g, __bf16* l) {
  auto* lp = (__attribute__((address_space(3))) char*)(uintptr_t)(l);
  auto* gp = (const __attribute__((address_space(1))) char*)(g);
  __builtin_amdgcn_global_load_lds(gp, lp, 16, 0, 0);
}

__device__ static inline unsigned pkbf(float a, float b) {
  union { __bf16 h[2]; unsigned u; } v;
  v.h[0] = (__bf16)a; v.h[1] = (__bf16)b;
  return v.u;
}

// ---------------------------------------------------------------- casts
__global__ __launch_bounds__(256) void k_cast_x(const float* __restrict__ x,
                                                __bf16* __restrict__ xb, int n) {
  int idx = blockIdx.x * 256 + threadIdx.x;
  if (idx < n) xb[idx] = (__bf16)x[idx];
}

// dst[n][k] = src[k][n]; src (K,N) f32, dst (NP,K) bf16, zero-fill n in [N,NP)
__global__ __launch_bounds__(256) void k_tcast(const float* __restrict__ src,
                                               __bf16* __restrict__ dst,
                                               int K, int N, int NP) {
  __shared__ float tile[32][33];
  int k0 = blockIdx.x * 32;
  int n0 = blockIdx.y * 32;
  int tx = threadIdx.x & 31, ty = threadIdx.x >> 5;
  for (int i = ty; i < 32; i += 8) {
    int n = n0 + tx;
    tile[i][tx] = (n < N) ? src[(size_t)(k0 + i) * N + n] : 0.0f;
  }
  __syncthreads();
  for (int i = ty; i < 32; i += 8) {
    dst[(size_t)(n0 + i) * K + k0 + tx] = (__bf16)tile[tx][i];
  }
}

// dst[n][kc] = Wo[(kc>>6)*128 + (kc&63)][n]; dst (2048,1024) bf16
__global__ __launch_bounds__(256) void k_tcast_wo(const float* __restrict__ Wo,
                                                  __bf16* __restrict__ dst) {
  __shared__ float tile[32][33];
  int kc0 = blockIdx.x * 32;
  int n0  = blockIdx.y * 32;
  int rbase = (kc0 >> 6) * 128 + (kc0 & 63);
  int tx = threadIdx.x & 31, ty = threadIdx.x >> 5;
  for (int i = ty; i < 32; i += 8)
    tile[i][tx] = Wo[(size_t)(rbase + i) * C_ + n0 + tx];
  __syncthreads();
  for (int i = ty; i < 32; i += 8)
    dst[(size_t)(n0 + i) * 1024 + kc0 + tx] = (__bf16)tile[tx][i];
}

// ---------------------------------------------------------------- GEMM cores
// Transposed-accumulator core: acc[j][i] = (B-tile rows as A-op, A-tile rows
// as B-op). Per lane: n = bn*128 + wc + j*16 + quad*4 + r  (4 consecutive n!),
//                     m = bm*128 + wr + i*16 + fr.
// Double-buffered global_load_lds staging (round-4 validated).
__device__ static inline void gemm_core_T(const __bf16* __restrict__ A,
                                          const __bf16* __restrict__ B,
                                          int K, f32x4 (&acc)[4][4]) {
  __shared__ __align__(16) __bf16 As[2][128 * 32];
  __shared__ __align__(16) __bf16 Bs[2][128 * 32];
  const int tid  = threadIdx.x;
  const int lane = tid & 63;
  const int wave = tid >> 6;
  const int bm = blockIdx.x, bn = blockIdx.y;
  const int r0 = tid >> 2;
  const int c8 = (tid & 3) * 8;
  const __bf16* Ag = A + (size_t)(bm * 128 + r0) * K + c8;
  const __bf16* Bg = B + (size_t)(bn * 128 + r0) * K + c8;
  const int wr = (wave >> 1) * 64, wc = (wave & 1) * 64;
  const int fr = lane & 15, fk = (lane >> 4) * 8;
  const f32x4 fzero = {0.f, 0.f, 0.f, 0.f};
#pragma unroll
  for (int i = 0; i < 4; ++i)
#pragma unroll
    for (int j = 0; j < 4; ++j) acc[i][j] = fzero;

  load_lds16(Ag,                  &As[0][tid * 8]);
  load_lds16(Ag + (size_t)64 * K, &As[0][tid * 8 + 2048]);
  load_lds16(Bg,                  &Bs[0][tid * 8]);
  load_lds16(Bg + (size_t)64 * K, &Bs[0][tid * 8 + 2048]);

  int buf = 0;
  for (int k0 = 0; k0 < K; k0 += 32) {
    __syncthreads();
    if (k0 + 32 < K) {
      const int nb = buf ^ 1;
      load_lds16(Ag + k0 + 32,                  &As[nb][tid * 8]);
      load_lds16(Ag + (size_t)64 * K + k0 + 32, &As[nb][tid * 8 + 2048]);
      load_lds16(Bg + k0 + 32,                  &Bs[nb][tid * 8]);
      load_lds16(Bg + (size_t)64 * K + k0 + 32, &Bs[nb][tid * 8 + 2048]);
    }
    bf16x8 af[4], bfg[4];
#pragma unroll
    for (int i = 0; i < 4; ++i) af[i]  = *(const bf16x8*)&As[buf][(wr + i * 16 + fr) * 32 + fk];
#pragma unroll
    for (int j = 0; j < 4; ++j) bfg[j] = *(const bf16x8*)&Bs[buf][(wc + j * 16 + fr) * 32 + fk];
#pragma unroll
    for (int j = 0; j < 4; ++j)
#pragma unroll
      for (int i = 0; i < 4; ++i)
        acc[j][i] = MFMA16(bfg[j], af[i], acc[j][i]);
    buf ^= 1;
  }
}

__device__ static inline void rope_rot(float& v0, float& v1, float& v2, float& v3,
                                       int t, int d) {
  // pairs (d,d+1) and (d+2,d+3); d relative to rope base, even
  float fa = exp2f(-((float)d        / 64.0f) * LOG2_THETA);
  float fb = exp2f(-((float)(d + 2)  / 64.0f) * LOG2_THETA);
  float anga = (float)t * fa, angb = (float)t * fb;
  float ca = cosf(anga), sa = sinf(anga);
  float cb = cosf(angb), sb = sinf(angb);
  float o0 = v0 * ca - v1 * sa, o1 = v0 * sa + v1 * ca;
  float o2 = v2 * cb - v3 * sb, o3 = v2 * sb + v3 * cb;
  v0 = o0; v1 = o1; v2 = o2; v3 = o3;
}

// x@Wq fused with rope + softmax-scale -> qf [bh][t][128] bf16 (pre-scaled)
__global__ __launch_bounds__(256) void k_gemm_q(const __bf16* __restrict__ A,
                                                const __bf16* __restrict__ B,
                                                __bf16* __restrict__ qf) {
  f32x4 acc[4][4];
  gemm_core_T(A, B, 2048, acc);
  const int tid = threadIdx.x;
  const int lane = tid & 63, wave = tid >> 6;
  const int quad = lane >> 4, fr = lane & 15;
  const int wr = (wave >> 1) * 64, wc = (wave & 1) * 64;
  const float scale2 = 1.4426950408889634f / sqrtf(128.0f);
#pragma unroll
  for (int j = 0; j < 4; ++j) {
#pragma unroll
    for (int i = 0; i < 4; ++i) {
      int n0 = blockIdx.y * 128 + wc + j * 16 + quad * 4;
      int mm = blockIdx.x * 128 + wr + i * 16 + fr;
      int d = n0 & 127, h = (n0 >> 7) & 15;
      int b = mm >> 11, t = mm & 2047;
      float v0 = acc[j][i][0], v1 = acc[j][i][1];
      float v2 = acc[j][i][2], v3 = acc[j][i][3];
      if (d >= 64) rope_rot(v0, v1, v2, v3, t, d - 64);
      union { unsigned u[2]; uint2 uu; } o;
      o.u[0] = pkbf(v0 * scale2, v1 * scale2);
      o.u[1] = pkbf(v2 * scale2, v3 * scale2);
      *(uint2*)(qf + (((size_t)(b * 16 + h)) * 2048 + t) * 128 + d) = o.uu;
    }
  }
}

// x@Wkva fused: cols<512 -> kvl bf16; cols 512..575 -> rope, dup-write kf rope half
__global__ __launch_bounds__(256) void k_gemm_kva(const __bf16* __restrict__ A,
                                                  const __bf16* __restrict__ B,
                                                  __bf16* __restrict__ kvl,
                                                  __bf16* __restrict__ kf) {
  f32x4 acc[4][4];
  gemm_core_T(A, B, 2048, acc);
  const int tid = threadIdx.x;
  const int lane = tid & 63, wave = tid >> 6;
  const int quad = lane >> 4, fr = lane & 15;
  const int wr = (wave >> 1) * 64, wc = (wave & 1) * 64;
#pragma unroll
  for (int j = 0; j < 4; ++j) {
#pragma unroll
    for (int i = 0; i < 4; ++i) {
      int n0 = blockIdx.y * 128 + wc + j * 16 + quad * 4;
      int mm = blockIdx.x * 128 + wr + i * 16 + fr;
      float v0 = acc[j][i][0], v1 = acc[j][i][1];
      float v2 = acc[j][i][2], v3 = acc[j][i][3];
      if (n0 < 512) {
        union { unsigned u[2]; uint2 uu; } o;
        o.u[0] = pkbf(v0, v1);
        o.u[1] = pkbf(v2, v3);
        *(uint2*)(kvl + (size_t)mm * 512 + n0) = o.uu;
      } else if (n0 < 576) {
        int d = n0 - 512;
        int b = mm >> 11, t = mm & 2047;
        rope_rot(v0, v1, v2, v3, t, d);
        union { unsigned u[2]; uint2 uu; } o;
        o.u[0] = pkbf(v0, v1);
        o.u[1] = pkbf(v2, v3);
#pragma unroll
        for (int h = 0; h < 16; ++h)
          *(uint2*)(kf + (((size_t)(b * 16 + h)) * 2048 + t) * 128 + 64 + d) = o.uu;
      }
    }
  }
}

// kvl@Wkvb fused -> kf nope half [bh][t][0:64] bf16
__global__ __launch_bounds__(256) void k_gemm_kvb(const __bf16* __restrict__ A,
                                                  const __bf16* __restrict__ B,
                                                  __bf16* __restrict__ kf) {
  f32x4 acc[4][4];
  gemm_core_T(A, B, 512, acc);
  const int tid = threadIdx.x;
  const int lane = tid & 63, wave = tid >> 6;
  const int quad = lane >> 4, fr = lane & 15;
  const int wr = (wave >> 1) * 64, wc = (wave & 1) * 64;
#pragma unroll
  for (int j = 0; j < 4; ++j) {
#pragma unroll
    for (int i = 0; i < 4; ++i) {
      int n0 = blockIdx.y * 128 + wc + j * 16 + quad * 4;
      int mm = blockIdx.x * 128 + wr + i * 16 + fr;
      int h = n0 >> 6, d = n0 & 63;
      int b = mm >> 11, t = mm & 2047;
      union { unsigned u[2]; uint2 uu; } o;
      o.u[0] = pkbf(acc[j][i][0], acc[j][i][1]);
      o.u[1] = pkbf(acc[j][i][2], acc[j][i][3]);
      *(uint2*)(kf + (((size_t)(b * 16 + h)) * 2048 + t) * 128 + d) = o.uu;
    }
  }
}

// Standard-layout GEMM for the f32 output projection (unchanged from round 4)
__global__ __launch_bounds__(256) void k_gemm_bt(const __bf16* __restrict__ A,
                                                 const __bf16* __restrict__ B,
                                                 float* __restrict__ C,
                                                 int M, int N, int K) {
  __shared__ __align__(16) __bf16 As[2][128 * 32];
  __shared__ __align__(16) __bf16 Bs[2][128 * 32];
  const int tid  = threadIdx.x;
  const int lane = tid & 63;
  const int wave = tid >> 6;
  const int bm = blockIdx.x, bn = blockIdx.y;
  const int r0 = tid >> 2;
  const int c8 = (tid & 3) * 8;
  const __bf16* Ag = A + (size_t)(bm * 128 + r0) * K + c8;
  const __bf16* Bg = B + (size_t)(bn * 128 + r0) * K + c8;
  const int wr = (wave >> 1) * 64, wc = (wave & 1) * 64;
  const int fr = lane & 15, fk = (lane >> 4) * 8;
  const f32x4 fzero = {0.f, 0.f, 0.f, 0.f};
  f32x4 acc[4][4];
#pragma unroll
  for (int i = 0; i < 4; ++i)
#pragma unroll
    for (int j = 0; j < 4; ++j) acc[i][j] = fzero;

  load_lds16(Ag,                  &As[0][tid * 8]);
  load_lds16(Ag + (size_t)64 * K, &As[0][tid * 8 + 2048]);
  load_lds16(Bg,                  &Bs[0][tid * 8]);
  load_lds16(Bg + (size_t)64 * K, &Bs[0][tid * 8 + 2048]);

  int buf = 0;
  for (int k0 = 0; k0 < K; k0 += 32) {
    __syncthreads();
    if (k0 + 32 < K) {
      const int nb = buf ^ 1;
      load_lds16(Ag + k0 + 32,                  &As[nb][tid * 8]);
      load_lds16(Ag + (size_t)64 * K + k0 + 32, &As[nb][tid * 8 + 2048]);
      load_lds16(Bg + k0 + 32,                  &Bs[nb][tid * 8]);
      load_lds16(Bg + (size_t)64 * K + k0 + 32, &Bs[nb][tid * 8 + 2048]);
    }
    bf16x8 af[4], bfg[4];
#pragma unroll
    for (int i = 0; i < 4; ++i) af[i]  = *(const bf16x8*)&As[buf][(wr + i * 16 + fr) * 32 + fk];
#pragma unroll
    for (int j = 0; j < 4; ++j) bfg[j] = *(const bf16x8*)&Bs[buf][(wc + j * 16 + fr) * 32 + fk];
#pragma unroll
    for (int i = 0; i < 4; ++i)
#pragma unroll
      for (int j = 0; j < 4; ++j)
        acc[i][j] = MFMA16(af[i], bfg[j], acc[i][j]);
    buf ^= 1;
  }
  const int rbase = (lane >> 4) * 4;
  float* Cb = C + (size_t)(bm * 128 + wr + rbase) * N + bn * 128 + wc + fr;
#pragma unroll
  for (int i = 0; i < 4; ++i)
#pragma unroll
    for (int j = 0; j < 4; ++j)
#pragma unroll
      for (int r = 0; r < 4; ++r)
        Cb[(size_t)(i * 16 + r) * N + j * 16] = acc[i][j][r];
}

// kf [bh][t][0:64] -> kvT [bh][d][t]
__global__ __launch_bounds__(256) void k_build_kvT(const __bf16* __restrict__ kf,
                                                   __bf16* __restrict__ kvT) {
  __shared__ __bf16 tile[64][68];
  const int bh = blockIdx.x;
  const int t0 = blockIdx.y * 64;
  const int tid = threadIdx.x;
  const int i0 = tid >> 4, d4 = (tid & 15) * 4;
#pragma unroll
  for (int p = 0; p < 4; ++p) {
    int i = i0 + p * 16;
    union { uint2 v; __bf16 h[4]; } ld;
    ld.v = *(const uint2*)(kf + ((size_t)bh * T_ + t0 + i) * 128 + d4);
    tile[i][d4] = ld.h[0]; tile[i][d4 + 1] = ld.h[1];
    tile[i][d4 + 2] = ld.h[2]; tile[i][d4 + 3] = ld.h[3];
  }
  __syncthreads();
  const int dd = tid >> 2, tc0 = (tid & 3) * 16;
  __bf16 outv[16];
#pragma unroll
  for (int j = 0; j < 16; ++j) outv[j] = tile[tc0 + j][dd];
  __bf16* dst = kvT + ((size_t)(bh * 64 + dd)) * T_ + t0 + tc0;
  *(bf16x8*)dst = *(bf16x8*)&outv[0];
  *(bf16x8*)(dst + 8) = *(bf16x8*)&outv[8];
}

// ---------------------------------------------------------------- attention
// S^T formulation; qf is PRE-SCALED by log2e/sqrt(128) (folded in k_gemm_q).
// Full (unmasked) tiles skip the causal-mask VALU via a wave-uniform branch.
__global__ __launch_bounds__(256, 4) void k_attn(const __bf16* __restrict__ qf,
                                                 const __bf16* __restrict__ kf,
                                                 const __bf16* __restrict__ kvT,
                                                 __bf16* __restrict__ yc) {
  const int blk = blockIdx.x;          // 1024 = 32 qt * 32 bh
  const int bh = blk & 31;             // bh mod 8 == XCD -> per-XCD L2 locality
  const int qt = 31 - (blk >> 5);      // heavy tiles first
  const int b = bh >> 4, h = bh & 15;
  const int qbase = qt * 64;
  const int tid = threadIdx.x;
  const int lane = tid & 63, wave = tid >> 6;
  const int fr = lane & 15, quad = lane >> 4, fk8 = quad * 8;

  __shared__ __align__(16) __bf16 Ks[64][136];
  __shared__ __align__(16) __bf16 VsT[64][72];

  const int qi = qbase + wave * 16 + fr;
  const __bf16* qb = qf + ((size_t)bh * T_ + qi) * HD_;
  bf16x8 aq[4];
#pragma unroll
  for (int g = 0; g < 4; ++g) aq[g] = *(const bf16x8*)(qb + g * 32 + fk8);

  const f32x4 fzero = {0.f, 0.f, 0.f, 0.f};
  f32x4 accO[4];
#pragma unroll
  for (int g = 0; g < 4; ++g) accO[g] = fzero;
  float m = -1e30f, l = 0.f;

  const int srow = tid >> 4, scol = (tid & 15) * 8;
  const int vrow = tid >> 3, vcol = (tid & 7) * 8;
  const __bf16* kbh = kf + (size_t)bh * T_ * 128;
  const __bf16* vbh = kvT + (size_t)bh * 64 * T_;
  const int srcA = (quad & 1) * 32 + fr, srcB = srcA + 16;
  const int hi = quad >> 1;

  for (int s0 = 0; s0 <= qbase; s0 += 64) {
    __syncthreads();
#pragma unroll
    for (int p = 0; p < 4; ++p)
      *(bf16x8*)&Ks[srow + p * 16][scol] =
        *(const bf16x8*)(kbh + (size_t)(s0 + srow + p * 16) * 128 + scol);
#pragma unroll
    for (int p = 0; p < 2; ++p)
      *(bf16x8*)&VsT[vrow + p * 32][vcol] =
        *(const bf16x8*)(vbh + (size_t)(vrow + p * 32) * T_ + s0 + vcol);
    __syncthreads();

    f32x4 accST[4];
#pragma unroll
    for (int cg = 0; cg < 4; ++cg) accST[cg] = fzero;
#pragma unroll
    for (int cg = 0; cg < 4; ++cg) {
#pragma unroll
      for (int kg = 0; kg < 4; ++kg) {
        bf16x8 bk = *(const bf16x8*)&Ks[cg * 16 + fr][kg * 32 + fk8];
        accST[cg] = MFMA16(bk, aq[kg], accST[cg]);
      }
    }

    // wave-uniform: tile fully below diagonal for every lane of this wave?
    const bool full = (s0 + 63 <= qbase + wave * 16);
    if (!full) {
#pragma unroll
      for (int cg = 0; cg < 4; ++cg)
#pragma unroll
        for (int r = 0; r < 4; ++r) {
          const int key = s0 + cg * 16 + quad * 4 + r;
          accST[cg][r] = (key <= qi) ? accST[cg][r] : -1e30f;
        }
    }
    float lmax = -1e30f;
#pragma unroll
    for (int cg = 0; cg < 4; ++cg)
#pragma unroll
      for (int r = 0; r < 4; ++r) lmax = fmaxf(lmax, accST[cg][r]);
    lmax = fmaxf(lmax, __shfl_xor(lmax, 16, 64));
    lmax = fmaxf(lmax, __shfl_xor(lmax, 32, 64));
    const float mn = fmaxf(m, lmax);
    const float alpha = exp2f(m - mn);
    m = mn;

    float lsum = 0.f;
    unsigned pk0[4], pk1[4];
#pragma unroll
    for (int cg = 0; cg < 4; ++cg) {
      float p0 = exp2f(accST[cg][0] - m);
      float p1 = exp2f(accST[cg][1] - m);
      float p2 = exp2f(accST[cg][2] - m);
      float p3 = exp2f(accST[cg][3] - m);
      lsum += (p0 + p1) + (p2 + p3);
      pk0[cg] = pkbf(p0, p1);
      pk1[cg] = pkbf(p2, p3);
    }
    lsum += __shfl_xor(lsum, 16, 64);
    lsum += __shfl_xor(lsum, 32, 64);
    l = l * alpha + lsum;
#pragma unroll
    for (int g = 0; g < 4; ++g)
#pragma unroll
      for (int r = 0; r < 4; ++r) accO[g][r] *= alpha;

#pragma unroll
    for (int ks = 0; ks < 2; ++ks) {
      int a0 = __shfl((int)pk0[2 * ks], srcA, 64);
      int b0 = __shfl((int)pk0[2 * ks + 1], srcA, 64);
      int a1 = __shfl((int)pk1[2 * ks], srcA, 64);
      int b1 = __shfl((int)pk1[2 * ks + 1], srcA, 64);
      int a2 = __shfl((int)pk0[2 * ks], srcB, 64);
      int b2 = __shfl((int)pk0[2 * ks + 1], srcB, 64);
      int a3 = __shfl((int)pk1[2 * ks], srcB, 64);
      int b3 = __shfl((int)pk1[2 * ks + 1], srcB, 64);
      union { int i[4]; bf16x8 v; } pf;
      pf.i[0] = hi ? b0 : a0;
      pf.i[1] = hi ? b1 : a1;
      pf.i[2] = hi ? b2 : a2;
      pf.i[3] = hi ? b3 : a3;
#pragma unroll
      for (int g = 0; g < 4; ++g) {
        bf16x8 vv = *(const bf16x8*)&VsT[g * 16 + fr][ks * 32 + fk8];
        accO[g] = MFMA16(vv, pf.v, accO[g]);
      }
    }
  }

  const float linv = 1.0f / l;
  __bf16* yb = yc + ((size_t)(b * T_ + qi)) * 1024 + h * 64 + quad * 4;
#pragma unroll
  for (int g = 0; g < 4; ++g) {
    union { unsigned u[2]; uint2 v; } o;
    o.u[0] = pkbf(accO[g][0] * linv, accO[g][1] * linv);
    o.u[1] = pkbf(accO[g][2] * linv, accO[g][3] * linv);
    *(uint2*)(yb + g * 16) = o.v;
  }
}

// ---------------------------------------------------------------- launch
extern "C" void kernel_launch(void* const* d_in, const int* in_sizes, int n_in,
                              void* d_out, int out_size, void* d_ws, size_t ws_size,
                              hipStream_t stream) {
  const float* x    = (const float*)d_in[0];
  const float* Wq   = (const float*)d_in[1];
  const float* Wkva = (const float*)d_in[2];
  const float* Wkvb = (const float*)d_in[3];
  const float* Wo   = (const float*)d_in[4];
  float* out = (float*)d_out;
  char* ws = (char*)d_ws;

  // workspace layout (bytes) — all-bf16 pipeline, ~88 MB
  size_t off = 0;
  __bf16* xb    = (__bf16*)(ws + off); off += (size_t)BT_ * C_ * 2;          // 16.78M
  __bf16* WqT   = (__bf16*)(ws + off); off += (size_t)2048 * 2048 * 2;       // 8.39M
  __bf16* WkvaT = (__bf16*)(ws + off); off += (size_t)NKVAP_ * 2048 * 2;     // 2.62M
  __bf16* WkvbT = (__bf16*)(ws + off); off += (size_t)1024 * 512 * 2;        // 1.05M
  __bf16* WoTc  = (__bf16*)(ws + off); off += (size_t)2048 * 1024 * 2;       // 4.19M
  __bf16* kvl   = (__bf16*)(ws + off); off += (size_t)BT_ * 512 * 2;         // 4.19M
  __bf16* qfb   = (__bf16*)(ws + off); off += (size_t)B_ * H_ * T_ * HD_ * 2;// 16.78M
  __bf16* kfb   = (__bf16*)(ws + off); off += (size_t)B_ * H_ * T_ * HD_ * 2;// 16.78M
  __bf16* kvT   = (__bf16*)(ws + off); off += (size_t)B_ * H_ * 64 * T_ * 2; // 8.39M
  __bf16* yc    = (__bf16*)(ws + off); off += (size_t)BT_ * 1024 * 2;        // 8.39M

  // 1. casts / transposes
  k_cast_x<<<(BT_ * C_) / 256, 256, 0, stream>>>(x, xb, BT_ * C_);
  k_tcast<<<dim3(2048 / 32, 2048 / 32), 256, 0, stream>>>(Wq, WqT, 2048, 2048, 2048);
  k_tcast<<<dim3(2048 / 32, NKVAP_ / 32), 256, 0, stream>>>(Wkva, WkvaT, 2048, NKVA_, NKVAP_);
  k_tcast<<<dim3(512 / 32, 1024 / 32), 256, 0, stream>>>(Wkvb, WkvbT, 512, 1024, 1024);
  k_tcast_wo<<<dim3(1024 / 32, 2048 / 32), 256, 0, stream>>>(Wo, WoTc);

  // 2. fused projections
  k_gemm_q<<<dim3(BT_ / 128, 2048 / 128), 256, 0, stream>>>(xb, WqT, qfb);
  k_gemm_kva<<<dim3(BT_ / 128, NKVAP_ / 128), 256, 0, stream>>>(xb, WkvaT, kvl, kfb);
  k_gemm_kvb<<<dim3(BT_ / 128, 1024 / 128), 256, 0, stream>>>(kvl, WkvbT, kfb);
  k_build_kvT<<<dim3(B_ * H_, T_ / 64), 256, 0, stream>>>(kfb, kvT);

  // 3. attention (1024 blocks, 64 q-rows each)
  k_attn<<<(T_ / 64) * B_ * H_, 256, 0, stream>>>(qfb, kfb, kvT, yc);

  // 4. output projection (f32 out)
  k_gemm_bt<<<dim3(BT_ / 128, 2048 / 128), 256, 0, stream>>>(yc, WoTc, out, BT_, 2048, 1024);
}

// Round 6
// 448.827 us; speedup vs baseline: 1.0268x; 1.0268x over previous
//
#include <hip/hip_runtime.h>
#include <hip/hip_bf16.h>
#include <math.h>

// Problem constants
#define B_ 2
#define T_ 2048
#define C_ 2048
#define H_ 16
#define HD_ 128
#define LORA_ 512
#define RD_ 64
#define ND_ 64
#define BT_ (B_*T_)            // 4096
#define NKVA_ 576              // LORA + RD
#define NKVAP_ 640             // padded to 128
#define LOG2_THETA 16.609640474436812f

typedef __bf16 bf16x8 __attribute__((ext_vector_type(8)));
typedef float  f32x4  __attribute__((ext_vector_type(4)));

#define MFMA16(a,b,c) __builtin_amdgcn_mfma_f32_16x16x32_bf16((a),(b),(c),0,0,0)

// global -> LDS direct 16B copy (lds dest must be wave-uniform base + lane*16)
__device__ static inline void load_lds16(const __bf16* g, __bf16* l) {
  auto* lp = (__attribute__((address_space(3))) char*)(uintptr_t)(l);
  auto* gp = (const __attribute__((address_space(1))) char*)(g);
  __builtin_amdgcn_global_load_lds(gp, lp, 16, 0, 0);
}

__device__ static inline unsigned pkbf(float a, float b) {
  union { __bf16 h[2]; unsigned u; } v;
  v.h[0] = (__bf16)a; v.h[1] = (__bf16)b;
  return v.u;
}

// ---------------------------------------------------------------- casts
__global__ __launch_bounds__(256) void k_cast_x(const float* __restrict__ x,
                                                __bf16* __restrict__ xb, int n) {
  int idx = blockIdx.x * 256 + threadIdx.x;
  if (idx < n) xb[idx] = (__bf16)x[idx];
}

// dst[n][k] = src[k][n]; src (K,N) f32, dst (NP,K) bf16, zero-fill n in [N,NP)
__global__ __launch_bounds__(256) void k_tcast(const float* __restrict__ src,
                                               __bf16* __restrict__ dst,
                                               int K, int N, int NP) {
  __shared__ float tile[32][33];
  int k0 = blockIdx.x * 32;
  int n0 = blockIdx.y * 32;
  int tx = threadIdx.x & 31, ty = threadIdx.x >> 5;
  for (int i = ty; i < 32; i += 8) {
    int n = n0 + tx;
    tile[i][tx] = (n < N) ? src[(size_t)(k0 + i) * N + n] : 0.0f;
  }
  __syncthreads();
  for (int i = ty; i < 32; i += 8) {
    dst[(size_t)(n0 + i) * K + k0 + tx] = (__bf16)tile[tx][i];
  }
}

// dst[n][kc] = Wo[(kc>>6)*128 + (kc&63)][n]; dst (2048,1024) bf16
__global__ __launch_bounds__(256) void k_tcast_wo(const float* __restrict__ Wo,
                                                  __bf16* __restrict__ dst) {
  __shared__ float tile[32][33];
  int kc0 = blockIdx.x * 32;
  int n0  = blockIdx.y * 32;
  int rbase = (kc0 >> 6) * 128 + (kc0 & 63);
  int tx = threadIdx.x & 31, ty = threadIdx.x >> 5;
  for (int i = ty; i < 32; i += 8)
    tile[i][tx] = Wo[(size_t)(rbase + i) * C_ + n0 + tx];
  __syncthreads();
  for (int i = ty; i < 32; i += 8)
    dst[(size_t)(n0 + i) * 1024 + kc0 + tx] = (__bf16)tile[tx][i];
}

// ---------------------------------------------------------------- GEMM cores
// Transposed-accumulator core on caller-provided LDS (As,Bs each 2x4096 bf16).
// acc[j][i]: n = bn*128 + wc + j*16 + quad*4 + r (4 consecutive n per lane),
//            m = bm*128 + wr + i*16 + fr.
__device__ static inline void gemm_core_T(const __bf16* __restrict__ A,
                                          const __bf16* __restrict__ B,
                                          int K, f32x4 (&acc)[4][4],
                                          __bf16* As, __bf16* Bs) {
  const int tid  = threadIdx.x;
  const int lane = tid & 63;
  const int wave = tid >> 6;
  const int bm = blockIdx.x, bn = blockIdx.y;
  const int r0 = tid >> 2;
  const int c8 = (tid & 3) * 8;
  const __bf16* Ag = A + (size_t)(bm * 128 + r0) * K + c8;
  const __bf16* Bg = B + (size_t)(bn * 128 + r0) * K + c8;
  const int wr = (wave >> 1) * 64, wc = (wave & 1) * 64;
  const int fr = lane & 15, fk = (lane >> 4) * 8;
  const f32x4 fzero = {0.f, 0.f, 0.f, 0.f};
#pragma unroll
  for (int i = 0; i < 4; ++i)
#pragma unroll
    for (int j = 0; j < 4; ++j) acc[i][j] = fzero;

  load_lds16(Ag,                  &As[tid * 8]);
  load_lds16(Ag + (size_t)64 * K, &As[tid * 8 + 2048]);
  load_lds16(Bg,                  &Bs[tid * 8]);
  load_lds16(Bg + (size_t)64 * K, &Bs[tid * 8 + 2048]);

  int buf = 0;
  for (int k0 = 0; k0 < K; k0 += 32) {
    __syncthreads();
    if (k0 + 32 < K) {
      const int nb = buf ^ 1;
      load_lds16(Ag + k0 + 32,                  &As[nb * 4096 + tid * 8]);
      load_lds16(Ag + (size_t)64 * K + k0 + 32, &As[nb * 4096 + tid * 8 + 2048]);
      load_lds16(Bg + k0 + 32,                  &Bs[nb * 4096 + tid * 8]);
      load_lds16(Bg + (size_t)64 * K + k0 + 32, &Bs[nb * 4096 + tid * 8 + 2048]);
    }
    bf16x8 af[4], bfg[4];
#pragma unroll
    for (int i = 0; i < 4; ++i) af[i]  = *(const bf16x8*)&As[buf * 4096 + (wr + i * 16 + fr) * 32 + fk];
#pragma unroll
    for (int j = 0; j < 4; ++j) bfg[j] = *(const bf16x8*)&Bs[buf * 4096 + (wc + j * 16 + fr) * 32 + fk];
#pragma unroll
    for (int j = 0; j < 4; ++j)
#pragma unroll
      for (int i = 0; i < 4; ++i)
        acc[j][i] = MFMA16(bfg[j], af[i], acc[j][i]);
    buf ^= 1;
  }
}

__device__ static inline void rope_rot(float& v0, float& v1, float& v2, float& v3,
                                       int t, int d) {
  float fa = exp2f(-((float)d       / 64.0f) * LOG2_THETA);
  float fb = exp2f(-((float)(d + 2) / 64.0f) * LOG2_THETA);
  float anga = (float)t * fa, angb = (float)t * fb;
  float ca = cosf(anga), sa = sinf(anga);
  float cb = cosf(angb), sb = sinf(angb);
  float o0 = v0 * ca - v1 * sa, o1 = v0 * sa + v1 * ca;
  float o2 = v2 * cb - v3 * sb, o3 = v2 * sb + v3 * cb;
  v0 = o0; v1 = o1; v2 = o2; v3 = o3;
}

#define SMEM_ELEMS 17408   // max(core 16384, epilogue 128*136)

// x@Wq fused rope+scale -> qf [bh][t][128] bf16 (pre-scaled); LDS-staged stores
__global__ __launch_bounds__(256) void k_gemm_q(const __bf16* __restrict__ A,
                                                const __bf16* __restrict__ B,
                                                __bf16* __restrict__ qf) {
  __shared__ __align__(16) __bf16 smem[SMEM_ELEMS];
  f32x4 acc[4][4];
  gemm_core_T(A, B, 2048, acc, smem, smem + 8192);
  const int tid = threadIdx.x;
  const int lane = tid & 63, wave = tid >> 6;
  const int quad = lane >> 4, fr = lane & 15;
  const int wr = (wave >> 1) * 64, wc = (wave & 1) * 64;
  const int bm = blockIdx.x;
  const float scale2 = 1.4426950408889634f / sqrtf(128.0f);
  __syncthreads();                       // done reading As/Bs; alias as Ct
  __bf16* Ct = smem;                     // [128][136]
#pragma unroll
  for (int j = 0; j < 4; ++j) {
#pragma unroll
    for (int i = 0; i < 4; ++i) {
      const int col = wc + j * 16 + quad * 4;   // = d
      const int row = wr + i * 16 + fr;
      const int t = (bm * 128 + row) & 2047;
      float v0 = acc[j][i][0], v1 = acc[j][i][1];
      float v2 = acc[j][i][2], v3 = acc[j][i][3];
      if (col >= 64) rope_rot(v0, v1, v2, v3, t, col - 64);
      union { unsigned u[2]; uint2 uu; } o;
      o.u[0] = pkbf(v0 * scale2, v1 * scale2);
      o.u[1] = pkbf(v2 * scale2, v3 * scale2);
      *(uint2*)&Ct[row * 136 + col] = o.uu;
    }
  }
  __syncthreads();
  const int b = (bm * 128) >> 11, t0 = (bm * 128) & 2047, h = blockIdx.y;
  __bf16* dst = qf + (((size_t)(b * 16 + h)) * 2048 + t0) * 128;
#pragma unroll
  for (int p = 0; p < 8; ++p) {
    const int rl = p * 16 + (tid >> 4);
    const int cc = (tid & 15) * 8;
    *(uint4*)(dst + (size_t)rl * 128 + cc) = *(const uint4*)&Ct[rl * 136 + cc];
  }
}

// x@Wkva fused: bn<4 -> kvl tile; bn==4 -> rope + 16-head dup into kf rope half
__global__ __launch_bounds__(256) void k_gemm_kva(const __bf16* __restrict__ A,
                                                  const __bf16* __restrict__ B,
                                                  __bf16* __restrict__ kvl,
                                                  __bf16* __restrict__ kf) {
  __shared__ __align__(16) __bf16 smem[SMEM_ELEMS];
  f32x4 acc[4][4];
  gemm_core_T(A, B, 2048, acc, smem, smem + 8192);
  const int tid = threadIdx.x;
  const int lane = tid & 63, wave = tid >> 6;
  const int quad = lane >> 4, fr = lane & 15;
  const int wr = (wave >> 1) * 64, wc = (wave & 1) * 64;
  const int bm = blockIdx.x, bn = blockIdx.y;
  const int b = (bm * 128) >> 11, t0 = (bm * 128) & 2047;
  __syncthreads();
  if (bn < 4) {
    __bf16* Ct = smem;                   // [128][136]
#pragma unroll
    for (int j = 0; j < 4; ++j)
#pragma unroll
      for (int i = 0; i < 4; ++i) {
        const int col = wc + j * 16 + quad * 4;
        const int row = wr + i * 16 + fr;
        union { unsigned u[2]; uint2 uu; } o;
        o.u[0] = pkbf(acc[j][i][0], acc[j][i][1]);
        o.u[1] = pkbf(acc[j][i][2], acc[j][i][3]);
        *(uint2*)&Ct[row * 136 + col] = o.uu;
      }
    __syncthreads();
#pragma unroll
    for (int p = 0; p < 8; ++p) {
      const int rl = p * 16 + (tid >> 4);
      const int cc = (tid & 15) * 8;
      *(uint4*)(kvl + (size_t)(bm * 128 + rl) * 512 + bn * 128 + cc) =
        *(const uint4*)&Ct[rl * 136 + cc];
    }
  } else {
    // cols 512..575 -> rope; 576+ is zero padding (skip). wc==64 waves hold pad.
    __bf16* Ct = smem;                   // [128][72]
    if (wc == 0) {                       // wave-uniform guard
#pragma unroll
      for (int j = 0; j < 4; ++j)
#pragma unroll
        for (int i = 0; i < 4; ++i) {
          const int col = j * 16 + quad * 4;    // d in [0,64)
          const int row = wr + i * 16 + fr;
          const int t = (bm * 128 + row) & 2047;
          float v0 = acc[j][i][0], v1 = acc[j][i][1];
          float v2 = acc[j][i][2], v3 = acc[j][i][3];
          rope_rot(v0, v1, v2, v3, t, col);
          union { unsigned u[2]; uint2 uu; } o;
          o.u[0] = pkbf(v0, v1);
          o.u[1] = pkbf(v2, v3);
          *(uint2*)&Ct[row * 72 + col] = o.uu;
        }
    }
    __syncthreads();
#pragma unroll
    for (int h = 0; h < 16; ++h) {
      __bf16* kbase = kf + (((size_t)(b * 16 + h)) * 2048 + t0) * 128 + 64;
#pragma unroll
      for (int p = 0; p < 4; ++p) {
        const int rl = p * 32 + (tid >> 3);
        const int cc = (tid & 7) * 8;
        *(uint4*)(kbase + (size_t)rl * 128 + cc) = *(const uint4*)&Ct[rl * 72 + cc];
      }
    }
  }
}

// kvl@Wkvb fused -> kf nope half [bh][t][0:64]; LDS-staged stores
__global__ __launch_bounds__(256) void k_gemm_kvb(const __bf16* __restrict__ A,
                                                  const __bf16* __restrict__ B,
                                                  __bf16* __restrict__ kf) {
  __shared__ __align__(16) __bf16 smem[SMEM_ELEMS];
  f32x4 acc[4][4];
  gemm_core_T(A, B, 512, acc, smem, smem + 8192);
  const int tid = threadIdx.x;
  const int lane = tid & 63, wave = tid >> 6;
  const int quad = lane >> 4, fr = lane & 15;
  const int wr = (wave >> 1) * 64, wc = (wave & 1) * 64;
  const int bm = blockIdx.x, bn = blockIdx.y;
  const int b = (bm * 128) >> 11, t0 = (bm * 128) & 2047;
  __syncthreads();
  __bf16* Ct = smem;                     // [128][136]
#pragma unroll
  for (int j = 0; j < 4; ++j)
#pragma unroll
    for (int i = 0; i < 4; ++i) {
      const int col = wc + j * 16 + quad * 4;
      const int row = wr + i * 16 + fr;
      union { unsigned u[2]; uint2 uu; } o;
      o.u[0] = pkbf(acc[j][i][0], acc[j][i][1]);
      o.u[1] = pkbf(acc[j][i][2], acc[j][i][3]);
      *(uint2*)&Ct[row * 136 + col] = o.uu;
    }
  __syncthreads();
  const int h0 = 2 * bn;
#pragma unroll
  for (int p = 0; p < 8; ++p) {
    const int idx = p * 256 + tid;
    const int chunk = idx & 7;           // 8 x 16B = 128B (64 d)
    const int hs = (idx >> 3) & 1;
    const int rl = idx >> 4;
    *(uint4*)(kf + (((size_t)(b * 16 + h0 + hs)) * 2048 + t0 + rl) * 128 + chunk * 8) =
      *(const uint4*)&Ct[rl * 136 + hs * 64 + chunk * 8];
  }
}

// Standard-layout GEMM for the f32 output projection
__global__ __launch_bounds__(256) void k_gemm_bt(const __bf16* __restrict__ A,
                                                 const __bf16* __restrict__ B,
                                                 float* __restrict__ C,
                                                 int M, int N, int K) {
  __shared__ __align__(16) __bf16 As[2][128 * 32];
  __shared__ __align__(16) __bf16 Bs[2][128 * 32];
  const int tid  = threadIdx.x;
  const int lane = tid & 63;
  const int wave = tid >> 6;
  const int bm = blockIdx.x, bn = blockIdx.y;
  const int r0 = tid >> 2;
  const int c8 = (tid & 3) * 8;
  const __bf16* Ag = A + (size_t)(bm * 128 + r0) * K + c8;
  const __bf16* Bg = B + (size_t)(bn * 128 + r0) * K + c8;
  const int wr = (wave >> 1) * 64, wc = (wave & 1) * 64;
  const int fr = lane & 15, fk = (lane >> 4) * 8;
  const f32x4 fzero = {0.f, 0.f, 0.f, 0.f};
  f32x4 acc[4][4];
#pragma unroll
  for (int i = 0; i < 4; ++i)
#pragma unroll
    for (int j = 0; j < 4; ++j) acc[i][j] = fzero;

  load_lds16(Ag,                  &As[0][tid * 8]);
  load_lds16(Ag + (size_t)64 * K, &As[0][tid * 8 + 2048]);
  load_lds16(Bg,                  &Bs[0][tid * 8]);
  load_lds16(Bg + (size_t)64 * K, &Bs[0][tid * 8 + 2048]);

  int buf = 0;
  for (int k0 = 0; k0 < K; k0 += 32) {
    __syncthreads();
    if (k0 + 32 < K) {
      const int nb = buf ^ 1;
      load_lds16(Ag + k0 + 32,                  &As[nb][tid * 8]);
      load_lds16(Ag + (size_t)64 * K + k0 + 32, &As[nb][tid * 8 + 2048]);
      load_lds16(Bg + k0 + 32,                  &Bs[nb][tid * 8]);
      load_lds16(Bg + (size_t)64 * K + k0 + 32, &Bs[nb][tid * 8 + 2048]);
    }
    bf16x8 af[4], bfg[4];
#pragma unroll
    for (int i = 0; i < 4; ++i) af[i]  = *(const bf16x8*)&As[buf][(wr + i * 16 + fr) * 32 + fk];
#pragma unroll
    for (int j = 0; j < 4; ++j) bfg[j] = *(const bf16x8*)&Bs[buf][(wc + j * 16 + fr) * 32 + fk];
#pragma unroll
    for (int i = 0; i < 4; ++i)
#pragma unroll
      for (int j = 0; j < 4; ++j)
        acc[i][j] = MFMA16(af[i], bfg[j], acc[i][j]);
    buf ^= 1;
  }
  const int rbase = (lane >> 4) * 4;
  float* Cb = C + (size_t)(bm * 128 + wr + rbase) * N + bn * 128 + wc + fr;
#pragma unroll
  for (int i = 0; i < 4; ++i)
#pragma unroll
    for (int j = 0; j < 4; ++j)
#pragma unroll
      for (int r = 0; r < 4; ++r)
        Cb[(size_t)(i * 16 + r) * N + j * 16] = acc[i][j][r];
}

// kf [bh][t][0:64] -> kvT [bh][d][t]
__global__ __launch_bounds__(256) void k_build_kvT(const __bf16* __restrict__ kf,
                                                   __bf16* __restrict__ kvT) {
  __shared__ __bf16 tile[64][68];
  const int bh = blockIdx.x;
  const int t0 = blockIdx.y * 64;
  const int tid = threadIdx.x;
  const int i0 = tid >> 4, d4 = (tid & 15) * 4;
#pragma unroll
  for (int p = 0; p < 4; ++p) {
    int i = i0 + p * 16;
    union { uint2 v; __bf16 h[4]; } ld;
    ld.v = *(const uint2*)(kf + ((size_t)bh * T_ + t0 + i) * 128 + d4);
    tile[i][d4] = ld.h[0]; tile[i][d4 + 1] = ld.h[1];
    tile[i][d4 + 2] = ld.h[2]; tile[i][d4 + 3] = ld.h[3];
  }
  __syncthreads();
  const int dd = tid >> 2, tc0 = (tid & 3) * 16;
  __bf16 outv[16];
#pragma unroll
  for (int j = 0; j < 16; ++j) outv[j] = tile[tc0 + j][dd];
  __bf16* dst = kvT + ((size_t)(bh * 64 + dd)) * T_ + t0 + tc0;
  *(bf16x8*)dst = *(bf16x8*)&outv[0];
  *(bf16x8*)(dst + 8) = *(bf16x8*)&outv[8];
}

// ---------------------------------------------------------------- attention
// S^T formulation; qf PRE-SCALED by log2e/sqrt(128). Full tiles skip mask VALU.
__global__ __launch_bounds__(256, 4) void k_attn(const __bf16* __restrict__ qf,
                                                 const __bf16* __restrict__ kf,
                                                 const __bf16* __restrict__ kvT,
                                                 __bf16* __restrict__ yc) {
  const int blk = blockIdx.x;          // 1024 = 32 qt * 32 bh
  const int bh = blk & 31;
  const int qt = 31 - (blk >> 5);
  const int b = bh >> 4, h = bh & 15;
  const int qbase = qt * 64;
  const int tid = threadIdx.x;
  const int lane = tid & 63, wave = tid >> 6;
  const int fr = lane & 15, quad = lane >> 4, fk8 = quad * 8;

  __shared__ __align__(16) __bf16 Ks[64][136];
  __shared__ __align__(16) __bf16 VsT[64][72];

  const int qi = qbase + wave * 16 + fr;
  const __bf16* qb = qf + ((size_t)bh * T_ + qi) * HD_;
  bf16x8 aq[4];
#pragma unroll
  for (int g = 0; g < 4; ++g) aq[g] = *(const bf16x8*)(qb + g * 32 + fk8);

  const f32x4 fzero = {0.f, 0.f, 0.f, 0.f};
  f32x4 accO[4];
#pragma unroll
  for (int g = 0; g < 4; ++g) accO[g] = fzero;
  float m = -1e30f, l = 0.f;

  const int srow = tid >> 4, scol = (tid & 15) * 8;
  const int vrow = tid >> 3, vcol = (tid & 7) * 8;
  const __bf16* kbh = kf + (size_t)bh * T_ * 128;
  const __bf16* vbh = kvT + (size_t)bh * 64 * T_;
  const int srcA = (quad & 1) * 32 + fr, srcB = srcA + 16;
  const int hi = quad >> 1;

  for (int s0 = 0; s0 <= qbase; s0 += 64) {
    __syncthreads();
#pragma unroll
    for (int p = 0; p < 4; ++p)
      *(bf16x8*)&Ks[srow + p * 16][scol] =
        *(const bf16x8*)(kbh + (size_t)(s0 + srow + p * 16) * 128 + scol);
#pragma unroll
    for (int p = 0; p < 2; ++p)
      *(bf16x8*)&VsT[vrow + p * 32][vcol] =
        *(const bf16x8*)(vbh + (size_t)(vrow + p * 32) * T_ + s0 + vcol);
    __syncthreads();

    f32x4 accST[4];
#pragma unroll
    for (int cg = 0; cg < 4; ++cg) accST[cg] = fzero;
#pragma unroll
    for (int cg = 0; cg < 4; ++cg) {
#pragma unroll
      for (int kg = 0; kg < 4; ++kg) {
        bf16x8 bk = *(const bf16x8*)&Ks[cg * 16 + fr][kg * 32 + fk8];
        accST[cg] = MFMA16(bk, aq[kg], accST[cg]);
      }
    }

    const bool full = (s0 + 63 <= qbase + wave * 16);
    if (!full) {
#pragma unroll
      for (int cg = 0; cg < 4; ++cg)
#pragma unroll
        for (int r = 0; r < 4; ++r) {
          const int key = s0 + cg * 16 + quad * 4 + r;
          accST[cg][r] = (key <= qi) ? accST[cg][r] : -1e30f;
        }
    }
    float lmax = -1e30f;
#pragma unroll
    for (int cg = 0; cg < 4; ++cg)
#pragma unroll
      for (int r = 0; r < 4; ++r) lmax = fmaxf(lmax, accST[cg][r]);
    lmax = fmaxf(lmax, __shfl_xor(lmax, 16, 64));
    lmax = fmaxf(lmax, __shfl_xor(lmax, 32, 64));
    const float mn = fmaxf(m, lmax);
    const float alpha = exp2f(m - mn);
    m = mn;

    float lsum = 0.f;
    unsigned pk0[4], pk1[4];
#pragma unroll
    for (int cg = 0; cg < 4; ++cg) {
      float p0 = exp2f(accST[cg][0] - m);
      float p1 = exp2f(accST[cg][1] - m);
      float p2 = exp2f(accST[cg][2] - m);
      float p3 = exp2f(accST[cg][3] - m);
      lsum += (p0 + p1) + (p2 + p3);
      pk0[cg] = pkbf(p0, p1);
      pk1[cg] = pkbf(p2, p3);
    }
    lsum += __shfl_xor(lsum, 16, 64);
    lsum += __shfl_xor(lsum, 32, 64);
    l = l * alpha + lsum;
#pragma unroll
    for (int g = 0; g < 4; ++g)
#pragma unroll
      for (int r = 0; r < 4; ++r) accO[g][r] *= alpha;

#pragma unroll
    for (int ks = 0; ks < 2; ++ks) {
      int a0 = __shfl((int)pk0[2 * ks], srcA, 64);
      int b0 = __shfl((int)pk0[2 * ks + 1], srcA, 64);
      int a1 = __shfl((int)pk1[2 * ks], srcA, 64);
      int b1 = __shfl((int)pk1[2 * ks + 1], srcA, 64);
      int a2 = __shfl((int)pk0[2 * ks], srcB, 64);
      int b2 = __shfl((int)pk0[2 * ks + 1], srcB, 64);
      int a3 = __shfl((int)pk1[2 * ks], srcB, 64);
      int b3 = __shfl((int)pk1[2 * ks + 1], srcB, 64);
      union { int i[4]; bf16x8 v; } pf;
      pf.i[0] = hi ? b0 : a0;
      pf.i[1] = hi ? b1 : a1;
      pf.i[2] = hi ? b2 : a2;
      pf.i[3] = hi ? b3 : a3;
#pragma unroll
      for (int g = 0; g < 4; ++g) {
        bf16x8 vv = *(const bf16x8*)&VsT[g * 16 + fr][ks * 32 + fk8];
        accO[g] = MFMA16(vv, pf.v, accO[g]);
      }
    }
  }

  const float linv = 1.0f / l;
  __bf16* yb = yc + ((size_t)(b * T_ + qi)) * 1024 + h * 64 + quad * 4;
#pragma unroll
  for (int g = 0; g < 4; ++g) {
    union { unsigned u[2]; uint2 v; } o;
    o.u[0] = pkbf(accO[g][0] * linv, accO[g][1] * linv);
    o.u[1] = pkbf(accO[g][2] * linv, accO[g][3] * linv);
    *(uint2*)(yb + g * 16) = o.v;
  }
}

// ---------------------------------------------------------------- launch
extern "C" void kernel_launch(void* const* d_in, const int* in_sizes, int n_in,
                              void* d_out, int out_size, void* d_ws, size_t ws_size,
                              hipStream_t stream) {
  const float* x    = (const float*)d_in[0];
  const float* Wq   = (const float*)d_in[1];
  const float* Wkva = (const float*)d_in[2];
  const float* Wkvb = (const float*)d_in[3];
  const float* Wo   = (const float*)d_in[4];
  float* out = (float*)d_out;
  char* ws = (char*)d_ws;

  size_t off = 0;
  __bf16* xb    = (__bf16*)(ws + off); off += (size_t)BT_ * C_ * 2;          // 16.78M
  __bf16* WqT   = (__bf16*)(ws + off); off += (size_t)2048 * 2048 * 2;       // 8.39M
  __bf16* WkvaT = (__bf16*)(ws + off); off += (size_t)NKVAP_ * 2048 * 2;     // 2.62M
  __bf16* WkvbT = (__bf16*)(ws + off); off += (size_t)1024 * 512 * 2;        // 1.05M
  __bf16* WoTc  = (__bf16*)(ws + off); off += (size_t)2048 * 1024 * 2;       // 4.19M
  __bf16* kvl   = (__bf16*)(ws + off); off += (size_t)BT_ * 512 * 2;         // 4.19M
  __bf16* qfb   = (__bf16*)(ws + off); off += (size_t)B_ * H_ * T_ * HD_ * 2;// 16.78M
  __bf16* kfb   = (__bf16*)(ws + off); off += (size_t)B_ * H_ * T_ * HD_ * 2;// 16.78M
  __bf16* kvT   = (__bf16*)(ws + off); off += (size_t)B_ * H_ * 64 * T_ * 2; // 8.39M
  __bf16* yc    = (__bf16*)(ws + off); off += (size_t)BT_ * 1024 * 2;        // 8.39M

  // 1. casts / transposes
  k_cast_x<<<(BT_ * C_) / 256, 256, 0, stream>>>(x, xb, BT_ * C_);
  k_tcast<<<dim3(2048 / 32, 2048 / 32), 256, 0, stream>>>(Wq, WqT, 2048, 2048, 2048);
  k_tcast<<<dim3(2048 / 32, NKVAP_ / 32), 256, 0, stream>>>(Wkva, WkvaT, 2048, NKVA_, NKVAP_);
  k_tcast<<<dim3(512 / 32, 1024 / 32), 256, 0, stream>>>(Wkvb, WkvbT, 512, 1024, 1024);
  k_tcast_wo<<<dim3(1024 / 32, 2048 / 32), 256, 0, stream>>>(Wo, WoTc);

  // 2. fused projections (coalesced LDS-staged epilogues)
  k_gemm_q<<<dim3(BT_ / 128, 2048 / 128), 256, 0, stream>>>(xb, WqT, qfb);
  k_gemm_kva<<<dim3(BT_ / 128, NKVAP_ / 128), 256, 0, stream>>>(xb, WkvaT, kvl, kfb);
  k_gemm_kvb<<<dim3(BT_ / 128, 1024 / 128), 256, 0, stream>>>(kvl, WkvbT, kfb);
  k_build_kvT<<<dim3(B_ * H_, T_ / 64), 256, 0, stream>>>(kfb, kvT);

  // 3. attention (1024 blocks, 64 q-rows each)
  k_attn<<<(T_ / 64) * B_ * H_, 256, 0, stream>>>(qfb, kfb, kvT, yc);

  // 4. output projection (f32 out)
  k_gemm_bt<<<dim3(BT_ / 128, 2048 / 128), 256, 0, stream>>>(yc, WoTc, out, BT_, 2048, 1024);
}